// Round 10
// baseline (2573.340 us; speedup 1.0000x reference)
//
#include <hip/hip_runtime.h>

#define SEQ 999
#define DTC 0.01f
#define NXW 125
#define NW1 64
// padded sync dword indices (128B stride)
#define IDX_C0  0
#define IDX_C1  32
#define IDX_CW1 64
#define IDX_FLG 96          // flag b at IDX_FLG + 32*b
#define SYNC_DWORDS 4096

typedef _Float16 h2 __attribute__((ext_vector_type(2)));

__device__ __forceinline__ h2 u2h(unsigned u){ return __builtin_bit_cast(h2,u); }

// v_pk_fma_f16 (VOP3P, full-rate): acc.lo += h.lo*w.lo ; acc.hi += h.hi*w.hi
// Weight tied ("+v") so it must stay register-resident (proven r5/r7/r8).
#define PKV(ACC,HV,WV) asm("v_pk_fma_f16 %0, %2, %1, %0" : "+v"(ACC), "+v"(WV) : "v"(HV))
// Weight from a plain VGPR (LDS-loaded or AGPR-read temp).
#define PKL(ACC,HV,WU) asm("v_pk_fma_f16 %0, %1, %2, %0" : "+v"(ACC) : "v"(WU), "v"(HV))
// AGPR init write (prologue only) and read (hot loop; VOP3P can't source AGPRs directly — r9 lesson).
#define AGW(AG,V) asm("v_accvgpr_write_b32 %0, %1" : "=a"(AG) : "v"(V))
#define AGR(T,AG) asm("v_accvgpr_read_b32 %0, %1" : "=v"(T) : "a"(AG))

__device__ __forceinline__ float softplusf(float x){
  return fmaxf(x,0.f) + log1pf(__expf(-fabsf(x)));
}
__device__ __forceinline__ float sigmoidf(float x){ return 1.f/(1.f+__expf(-x)); }
__device__ __forceinline__ float tanh_fast(float x){
  float e = __expf(-2.f*x); return (1.f-e)/(1.f+e);
}
__device__ __forceinline__ h2 pkfma(h2 a, h2 b, h2 c){
  return __builtin_elementwise_fma(a, b, c);
}

template<int SLP>
__device__ __forceinline__ void waitge(unsigned* p, unsigned v){
  if (__hip_atomic_load(p,__ATOMIC_RELAXED,__HIP_MEMORY_SCOPE_AGENT) < v){
    do { __builtin_amdgcn_s_sleep(SLP); }
    while (__hip_atomic_load(p,__ATOMIC_RELAXED,__HIP_MEMORY_SCOPE_AGENT) < v);
  }
  (void)__hip_atomic_load(p,__ATOMIC_ACQUIRE,__HIP_MEMORY_SCOPE_AGENT);
}

__global__ void k_init(unsigned* sync){
  for (int i=threadIdx.x; i<SYNC_DWORDS; i+=512) sync[i] = 0u;
}

// whh0/whh1 -> ROW-MAJOR f16 pairs wR[row*128+c2]; wih1 -> TRANSPOSED (for do_xw)
__global__ void k_convert(const float* __restrict__ whh0, const float* __restrict__ wih1,
                          const float* __restrict__ whh1,
                          const float* __restrict__ bih0, const float* __restrict__ bhh0,
                          const float* __restrict__ bih1, const float* __restrict__ bhh1,
                          h2* __restrict__ whh0R, h2* __restrict__ wih1T, h2* __restrict__ whh1R,
                          float* __restrict__ bs0, float* __restrict__ bs1){
  int o = blockIdx.x*256 + threadIdx.x;
  if (o < 131072){
    int r = o >> 7, c2 = o & 127;
    const float* s = whh0 + r*256 + 2*c2;
    whh0R[o] = h2{(_Float16)s[0], (_Float16)s[1]};
  } else if (o < 262144){
    int oo = o - 131072; int r = oo & 1023, c2 = oo >> 10;
    const float* s = wih1 + r*256 + 2*c2;
    wih1T[oo] = h2{(_Float16)s[0], (_Float16)s[1]};
  } else if (o < 393216){
    int oo = o - 262144; int r = oo >> 7, c2 = oo & 127;
    const float* s = whh1 + r*256 + 2*c2;
    whh1R[oo] = h2{(_Float16)s[0], (_Float16)s[1]};
  } else if (o < 394240){
    int r = o - 393216; bs0[r] = bih0[r] + bhh0[r];
  } else if (o < 395264){
    int r = o - 394240; bs1[r] = bih1[r] + bhh1[r];
  }
}

// ===== LSTM layer, ONE CU, K-split (r8 structure): thread (k=tid&255, half=tid>>8)
// owns unit k's 4 gate rows over h-cols [128*half,+128). Per row 64 h2:
// 16 VGPR + 32 AGPR (read via pipelined v_accvgpr_read) + 16 LDS.
// f16x2 accumulate, f32 flush every 16 pk per acc.

#define LOADROW(R, VV, AA) do{                                                      \
  const uint4* _src = (const uint4*)(wR + (size_t)((((R)<<8)+k)*128 + (half<<6)));  \
  _Pragma("unroll")                                                                 \
  for (int q=0;q<4;++q){ uint4 u=_src[q];                                           \
    VV[4*q]=u.x; VV[4*q+1]=u.y; VV[4*q+2]=u.z; VV[4*q+3]=u.w; }                     \
  _Pragma("unroll")                                                                 \
  for (int q=4;q<12;++q){ uint4 u=_src[q]; const int b=4*(q-4);                     \
    AGW(AA[b],u.x); AGW(AA[b+1],u.y); AGW(AA[b+2],u.z); AGW(AA[b+3],u.w); }         \
  _Pragma("unroll")                                                                 \
  for (int q=12;q<16;++q) wldsW[half][(R)*4+(q-12)][k] = _src[q];                   \
}while(0)

#define PK16V(J) do{                                                                 \
  PKV(pkI,hA.x,v0[J]);     PKV(pkF,hA.x,v1[J]);     PKV(pkG,hA.x,v2[J]);     PKV(pkO,hA.x,v3[J]);     \
  PKV(pkI,hA.y,v0[(J)+1]); PKV(pkF,hA.y,v1[(J)+1]); PKV(pkG,hA.y,v2[(J)+1]); PKV(pkO,hA.y,v3[(J)+1]); \
  PKV(pkI,hA.z,v0[(J)+2]); PKV(pkF,hA.z,v1[(J)+2]); PKV(pkG,hA.z,v2[(J)+2]); PKV(pkO,hA.z,v3[(J)+2]); \
  PKV(pkI,hA.w,v0[(J)+3]); PKV(pkF,hA.w,v1[(J)+3]); PKV(pkG,hA.w,v2[(J)+3]); PKV(pkO,hA.w,v3[(J)+3]); \
}while(0)

// AGPR weights: software-pipelined read-ahead (reads for quad n+1 issued before pk of quad n)
#define PK16A(J) do{                                                                 \
  unsigned tA0,tA1,tA2,tA3, tB0,tB1,tB2,tB3;                                         \
  AGR(tA0,a0g[J]);   AGR(tA1,a1g[J]);   AGR(tA2,a2g[J]);   AGR(tA3,a3g[J]);          \
  AGR(tB0,a0g[(J)+1]); AGR(tB1,a1g[(J)+1]); AGR(tB2,a2g[(J)+1]); AGR(tB3,a3g[(J)+1]);\
  PKL(pkI,hA.x,tA0); PKL(pkF,hA.x,tA1); PKL(pkG,hA.x,tA2); PKL(pkO,hA.x,tA3);        \
  AGR(tA0,a0g[(J)+2]); AGR(tA1,a1g[(J)+2]); AGR(tA2,a2g[(J)+2]); AGR(tA3,a3g[(J)+2]);\
  PKL(pkI,hA.y,tB0); PKL(pkF,hA.y,tB1); PKL(pkG,hA.y,tB2); PKL(pkO,hA.y,tB3);        \
  AGR(tB0,a0g[(J)+3]); AGR(tB1,a1g[(J)+3]); AGR(tB2,a2g[(J)+3]); AGR(tB3,a3g[(J)+3]);\
  PKL(pkI,hA.z,tA0); PKL(pkF,hA.z,tA1); PKL(pkG,hA.z,tA2); PKL(pkO,hA.z,tA3);        \
  PKL(pkI,hA.w,tB0); PKL(pkF,hA.w,tB1); PKL(pkG,hA.w,tB2); PKL(pkO,hA.w,tB3);        \
}while(0)

#define PK16L(C) do{                                                                 \
  uint4 u0=wldsW[half][0*4+(C)][k], u1=wldsW[half][1*4+(C)][k];                       \
  uint4 u2=wldsW[half][2*4+(C)][k], u3=wldsW[half][3*4+(C)][k];                       \
  PKL(pkI,hA.x,u0.x); PKL(pkF,hA.x,u1.x); PKL(pkG,hA.x,u2.x); PKL(pkO,hA.x,u3.x);    \
  PKL(pkI,hA.y,u0.y); PKL(pkF,hA.y,u1.y); PKL(pkG,hA.y,u2.y); PKL(pkO,hA.y,u3.y);    \
  PKL(pkI,hA.z,u0.z); PKL(pkF,hA.z,u1.z); PKL(pkG,hA.z,u2.z); PKL(pkO,hA.z,u3.z);    \
  PKL(pkI,hA.w,u0.w); PKL(pkF,hA.w,u1.w); PKL(pkG,hA.w,u2.w); PKL(pkO,hA.w,u3.w);    \
}while(0)

#define FLUSH() do{                                                \
  h2 _p0=u2h(pkI), _p1=u2h(pkF), _p2=u2h(pkG), _p3=u2h(pkO);       \
  ai += (float)_p0.x + (float)_p0.y; pkI=0;                        \
  af += (float)_p1.x + (float)_p1.y; pkF=0;                        \
  agv+= (float)_p2.x + (float)_p2.y; pkG=0;                        \
  ao += (float)_p3.x + (float)_p3.y; pkO=0;                        \
}while(0)

template<int MODE>
__device__ void do_layer(const h2* __restrict__ wR, const float* __restrict__ wih0,
                         const float* __restrict__ bs, const float* __restrict__ X,
                         const float* __restrict__ xw1,
                         _Float16* __restrict__ h0h, float* __restrict__ h1f,
                         unsigned* prog, unsigned* sync,
                         uint4 (*wldsW)[16][256], _Float16 (*hbufS)[256],
                         float4* pexch, float* xlds)
{
  const int tid  = threadIdx.x;
  const int k    = tid & 255;
  const int half = tid >> 8;

  unsigned v0[16], v1[16], v2[16], v3[16];     // 64 arch VGPR weights
  unsigned a0g[32], a1g[32], a2g[32], a3g[32]; // 128 AGPR weights
  LOADROW(0, v0, a0g);
  LOADROW(1, v1, a1g);
  LOADROW(2, v2, a2g);
  LOADROW(3, v3, a3g);

  float wxa0=0,wxa1=0,wxa2=0,wxa3=0, wxb0=0,wxb1=0,wxb2=0,wxb3=0, bv0=0,bv1=0,bv2=0,bv3=0;
  if (MODE==0){
    if (half==1){
      wxa0=wih0[((0<<8)+k)*2]; wxb0=wih0[((0<<8)+k)*2+1]; bv0=bs[(0<<8)+k];
      wxa1=wih0[((1<<8)+k)*2]; wxb1=wih0[((1<<8)+k)*2+1]; bv1=bs[(1<<8)+k];
      wxa2=wih0[((2<<8)+k)*2]; wxb2=wih0[((2<<8)+k)*2+1]; bv2=bs[(2<<8)+k];
      wxa3=wih0[((3<<8)+k)*2]; wxb3=wih0[((3<<8)+k)*2+1]; bv3=bs[(3<<8)+k];
    }
    for (int i=tid;i<2*SEQ;i+=512) xlds[i]=X[i];
  }
  if (tid < 256) hbufS[0][tid] = (_Float16)0.f;
  __syncthreads();

  float4 nx = {0,0,0,0}, nx2 = {0,0,0,0};
  if (MODE==1){
    if (tid==0) waitge<2>(&sync[IDX_FLG+0], 1u);
    __syncthreads();
    if (half==0) nx = *(const float4*)&xw1[(size_t)(k<<2)];
  }
  float c = 0.f;

#pragma unroll 1
  for (int t=0;t<SEQ;++t){
    if (MODE==1 && t+1<SEQ){
      if (((t+1)&7)==0){
        if (tid==0) waitge<2>(&sync[IDX_FLG + ((t+1)>>3)*32], 1u);
        __syncthreads();
      }
      if (half==0) nx2 = *(const float4*)&xw1[(size_t)(t+1)*1024 + (k<<2)];
    }

    float ai, af, agv, ao;
    if (MODE==0){
      if (half==1){
        float2 xv = *(const float2*)&xlds[2*t];
        ai = fmaf(wxb0, xv.y, fmaf(wxa0, xv.x, bv0));
        af = fmaf(wxb1, xv.y, fmaf(wxa1, xv.x, bv1));
        agv= fmaf(wxb2, xv.y, fmaf(wxa2, xv.x, bv2));
        ao = fmaf(wxb3, xv.y, fmaf(wxa3, xv.x, bv3));
      } else { ai=af=agv=ao=0.f; }
    } else {
      if (half==0){ ai=nx.x; af=nx.y; agv=nx.z; ao=nx.w; }
      else        { ai=af=agv=ao=0.f; }
    }

    // --- dot phase: 16 wave-uniform b128 h reads, 256 pk_fma, 4 f32 flushes ---
    unsigned pkI=0u, pkF=0u, pkG=0u, pkO=0u;
    const uint4* hb = (const uint4*)(&hbufS[t&1][0]) + (half<<4);
    uint4 hA = hb[0], hN;
    hN = hb[1];  PK16V(0);             hA = hN;
    hN = hb[2];  PK16V(4);             hA = hN;
    hN = hb[3];  PK16V(8);             hA = hN;
    hN = hb[4];  PK16V(12); FLUSH();   hA = hN;
    hN = hb[5];  PK16A(0);             hA = hN;
    hN = hb[6];  PK16A(4);             hA = hN;
    hN = hb[7];  PK16A(8);             hA = hN;
    hN = hb[8];  PK16A(12); FLUSH();   hA = hN;
    hN = hb[9];  PK16A(16);            hA = hN;
    hN = hb[10]; PK16A(20);            hA = hN;
    hN = hb[11]; PK16A(24);            hA = hN;
    hN = hb[12]; PK16A(28); FLUSH();   hA = hN;
    hN = hb[13]; PK16L(0);             hA = hN;
    hN = hb[14]; PK16L(1);             hA = hN;
    hN = hb[15]; PK16L(2);             hA = hN;
                 PK16L(3);  FLUSH();

    if (half==1) pexch[k] = float4{ai, af, agv, ao};
    __syncthreads();                                  // B1: partials ready
    if (half==0){
      float4 p = pexch[k];
      ai += p.x; af += p.y; agv += p.z; ao += p.w;
      float i_ = sigmoidf(ai), f_ = sigmoidf(af);
      float g_ = tanh_fast(agv), o_ = sigmoidf(ao);
      c = fmaf(f_, c, i_*g_);
      float h = o_ * tanh_fast(c);
      hbufS[(t+1)&1][k] = (_Float16)h;
      if (MODE==0) h0h[t*256+k] = (_Float16)h;
      else         h1f[t*256+k] = h;
      nx = nx2;
    }
    __syncthreads();                                  // B2: h visible, stores drained
    if (tid==0 && ((t&7)==7 || t==SEQ-1))
      __hip_atomic_store(prog,(unsigned)(t+1),__ATOMIC_RELEASE,__HIP_MEMORY_SCOPE_AGENT);
  }
}

// xw chunk worker; packed-fma with periodic f32 flush; output layout [t][unit][gate]
__device__ void do_xw(int b, const h2* __restrict__ wih1T, const float* __restrict__ bs1,
                      const _Float16* __restrict__ h0h, float* __restrict__ xw1,
                      unsigned* sync)
{
  const int tid = threadIdx.x;
  const int t0 = 8*b;
  const int tend = (t0+8 < SEQ) ? t0+8 : SEQ;
  if (tid==0) waitge<32>(&sync[IDX_C0], (unsigned)tend);
  __syncthreads();
  const float bA = bs1[tid], bB = bs1[tid+512];
  const int r0 = tid, r1 = tid + 512;
  const int d0 = ((r0&255)<<2) + (r0>>8);
  const int d1 = ((r1&255)<<2) + (r1>>8);
#pragma unroll 1
  for (int t=t0;t<tend;++t){
    const uint4* hv4 = (const uint4*)(h0h + (size_t)t*256);
    float a0=bA, a1=bB;
    h2 pa0={0,0}, pb0={0,0}, pa1={0,0}, pb1={0,0};
#pragma unroll
    for (int q=0;q<32;++q){
      uint4 hv = hv4[q];
      h2 hx=u2h(hv.x), hy=u2h(hv.y), hz=u2h(hv.z), hw=u2h(hv.w);
      pa0 = pkfma(hx, wih1T[(4*q+0)*1024+r0], pa0);
      pb0 = pkfma(hy, wih1T[(4*q+1)*1024+r0], pb0);
      pa0 = pkfma(hz, wih1T[(4*q+2)*1024+r0], pa0);
      pb0 = pkfma(hw, wih1T[(4*q+3)*1024+r0], pb0);
      pa1 = pkfma(hx, wih1T[(4*q+0)*1024+r1], pa1);
      pb1 = pkfma(hy, wih1T[(4*q+1)*1024+r1], pb1);
      pa1 = pkfma(hz, wih1T[(4*q+2)*1024+r1], pa1);
      pb1 = pkfma(hw, wih1T[(4*q+3)*1024+r1], pb1);
      if ((q&3)==3){
        a0 += (float)pa0.x + (float)pa0.y + (float)pb0.x + (float)pb0.y;
        a1 += (float)pa1.x + (float)pa1.y + (float)pb1.x + (float)pb1.y;
        pa0={0,0}; pb0={0,0}; pa1={0,0}; pb1={0,0};
      }
    }
    xw1[(size_t)t*1024 + d0] = a0;
    xw1[(size_t)t*1024 + d1] = a1;
  }
  __syncthreads();
  if (tid==0)
    __hip_atomic_store(&sync[IDX_FLG + 32*b], 1u, __ATOMIC_RELEASE, __HIP_MEMORY_SCOPE_AGENT);
}

// W1 streamer (proven r7/r8)
__device__ void do_w1(int w, const float* __restrict__ W1, const float* __restrict__ b1,
                      const float* __restrict__ h1f, float* __restrict__ z1,
                      unsigned* sync, float* red)
{
  const int tid = threadIdx.x;
#pragma unroll 1
  for (int rr=0;rr<4;++rr){
    const int j = w*4 + rr;
    const float* wrow = W1 + (size_t)j*(SEQ*256);
    float acc = 0.f;
#pragma unroll 1
    for (int kc=0;kc<8;++kc){
      const int lo = kc*128, hi = (kc==7) ? SEQ : lo+128;
      if (tid==0) waitge<64>(&sync[IDX_C1], (unsigned)hi);
      __syncthreads();
      const float4* w4 = (const float4*)(wrow + lo*256);
      const float4* h4 = (const float4*)(h1f + lo*256);
      const int n4 = (hi-lo)*64;
      for (int q=tid; q<n4; q+=512){
        float4 a=w4[q], b=h4[q];
        acc=fmaf(a.x,b.x,acc); acc=fmaf(a.y,b.y,acc);
        acc=fmaf(a.z,b.z,acc); acc=fmaf(a.w,b.w,acc);
      }
      __syncthreads();
    }
    red[tid]=acc; __syncthreads();
    for (int s=256;s>0;s>>=1){ if(tid<s) red[tid]+=red[tid+s]; __syncthreads(); }
    if (tid==0) z1[j] = softplusf(red[0] + b1[j]);
    __syncthreads();
  }
  if (tid==0)
    __hip_atomic_fetch_add(&sync[IDX_CW1], 1u, __ATOMIC_RELEASE, __HIP_MEMORY_SCOPE_AGENT);
}

__device__ void do_head(const float* __restrict__ W2, const float* __restrict__ b2,
                        const float* __restrict__ W3, const float* __restrict__ b3,
                        const float* __restrict__ z1, const float* __restrict__ data,
                        float* __restrict__ out, unsigned* sync, float* red)
{
  const int tid = threadIdx.x;
  if (tid==0) waitge<64>(&sync[IDX_CW1], (unsigned)NW1);
  __syncthreads();
  if (tid<256) red[tid] = z1[tid];
  __syncthreads();
  if (tid<128){
    float acc = b2[tid];
#pragma unroll 4
    for (int kk=0;kk<256;++kk) acc = fmaf(W2[tid*256+kk], red[kk], acc);
    red[256+tid] = softplusf(acc);
  }
  __syncthreads();
  if (tid<4){
    float a = b3[tid];
#pragma unroll 4
    for (int kk=0;kk<128;++kk) a = fmaf(W3[tid*128+kk], red[256+kk], a);
    red[384+tid] = a;
  }
  __syncthreads();
  if (tid==0){
    float a=red[384], b=red[385], cc=red[386], d=red[387];
    float R=data[0], J=data[1];
#pragma unroll 1
    for (int t=0;t<SEQ;++t){
      float RJ=R*J;
      float Rn = R + DTC*(a*R - b*RJ);
      float Jn = J + DTC*(d*RJ - cc*J);
      out[2*t]=Rn; out[2*t+1]=Jn;
      R=Rn; J=Jn;
    }
  }
}

// roles: 0=L0 | 1=L1 | 2..126 xw | 127..190 W1 | 191 head. ~143KB LDS -> 1 block/CU.
__global__ __launch_bounds__(512,1)
void k_fused(const h2* __restrict__ whh0R, const h2* __restrict__ wih1T,
             const h2* __restrict__ whh1R, const float* __restrict__ bs0,
             const float* __restrict__ bs1, const float* __restrict__ Wih0,
             const float* __restrict__ X, _Float16* h0h, float* xw1, float* h1f,
             float* z1, const float* __restrict__ W1, const float* __restrict__ b1,
             const float* __restrict__ W2, const float* __restrict__ b2,
             const float* __restrict__ W3, const float* __restrict__ b3,
             const float* __restrict__ data, float* out, unsigned* sync)
{
  __shared__ __align__(16) uint4 wldsW[2][16][256];    // 128 KB (LDS weight cols)
  __shared__ __align__(16) _Float16 hbufS[2][256];     // 1 KB double-buffered h
  __shared__ __align__(16) float4 pexch[256];          // 4 KB partial-sum exchange
  __shared__ float xlds[2*SEQ];                        // 8 KB
  __shared__ float red[512];                           // 2 KB (w1/head)

  const int role = blockIdx.x;
  if (role == 0)
    do_layer<0>(whh0R, Wih0, bs0, X, nullptr, h0h, nullptr,
                &sync[IDX_C0], sync, wldsW, hbufS, pexch, xlds);
  else if (role == 1)
    do_layer<1>(whh1R, nullptr, nullptr, nullptr, xw1, nullptr, h1f,
                &sync[IDX_C1], sync, wldsW, hbufS, pexch, xlds);
  else if (role < 2+NXW)
    do_xw(role-2, wih1T, bs1, h0h, xw1, sync);
  else if (role < 2+NXW+NW1)
    do_w1(role-(2+NXW), W1, b1, h1f, z1, sync, red);
  else
    do_head(W2, b2, W3, b3, z1, data, out, sync, red);
}

extern "C" void kernel_launch(void* const* d_in, const int* in_sizes, int n_in,
                              void* d_out, int out_size, void* d_ws, size_t ws_size,
                              hipStream_t stream){
  const float* X    = (const float*)d_in[0];
  const float* data = (const float*)d_in[1];
  const float* Wih0 = (const float*)d_in[2];
  const float* Whh0 = (const float*)d_in[3];
  const float* bih0 = (const float*)d_in[4];
  const float* bhh0 = (const float*)d_in[5];
  const float* Wih1 = (const float*)d_in[6];
  const float* Whh1 = (const float*)d_in[7];
  const float* bih1 = (const float*)d_in[8];
  const float* bhh1 = (const float*)d_in[9];
  const float* W1   = (const float*)d_in[10];
  const float* b1   = (const float*)d_in[11];
  const float* W2   = (const float*)d_in[12];
  const float* b2   = (const float*)d_in[13];
  const float* W3   = (const float*)d_in[14];
  const float* b3   = (const float*)d_in[15];
  float* out = (float*)d_out;

  char* w = (char*)d_ws;
  h2*       whh0R = (h2*)(w + 0);              // 512 KB row-major f16
  h2*       wih1T = (h2*)(w + 524288);         // 512 KB transposed f16
  h2*       whh1R = (h2*)(w + 1048576);        // 512 KB row-major f16
  float*    bs0   = (float*)(w + 1572864);     // 4 KB
  float*    bs1   = (float*)(w + 1576960);     // 4 KB
  _Float16* h0h   = (_Float16*)(w + 1581056);  // 511,488 B
  float*    xw1   = (float*)(w + 2097152);     // 4,091,904 B  [t][unit][gate]
  float*    h1f   = (float*)(w + 6189056);     // 1,022,976 B
  float*    z1    = (float*)(w + 7212032);     // 1 KB
  unsigned* sync  = (unsigned*)(w + 7213056);  // 16 KB padded counters/flags

  k_init<<<1, 512, 0, stream>>>(sync);
  k_convert<<<1544, 256, 0, stream>>>(Whh0, Wih1, Whh1, bih0, bhh0, bih1, bhh1,
                                      whh0R, wih1T, whh1R, bs0, bs1);
  k_fused<<<2+NXW+NW1+1, 512, 0, stream>>>(whh0R, wih1T, whh1R, bs0, bs1, Wih0, X,
                                           h0h, xw1, h1f, z1, W1, b1, W2, b2, W3, b3,
                                           data, out, sync);
}